// Round 7
// baseline (571.611 us; speedup 1.0000x reference)
//
#include <hip/hip_runtime.h>
#include <math.h>

#define D_FEAT 128
#define NB_HIST 64
#define N_NODES_MAX 10016   // LDS histogram capacity (problem has 10000)

// bf16 helpers -------------------------------------------------------------
__device__ __forceinline__ unsigned short f2bf(float x) {   // round-nearest-even
    unsigned int b = __float_as_uint(x);
    return (unsigned short)((b + 0x7fffu + ((b >> 16) & 1u)) >> 16);
}
__device__ __forceinline__ float2 bf2_to_f2(unsigned int u) {
    return make_float2(__uint_as_float(u << 16), __uint_as_float(u & 0xffff0000u));
}
__device__ __forceinline__ float dot_bf2(unsigned int a, unsigned int b) {
    float2 fa = bf2_to_f2(a), fb = bf2_to_f2(b);
    return fa.x * fb.x + fa.y * fb.y;
}

// ---------------------------------------------------------------------------
// 1. Fused grid:
//    blocks [0, NB_HIST): per-block LDS histogram of dst — NO global atomics.
//      lrank[e] = rank of e within (block, dst); hist[b*n_nodes+n] = count.
//    blocks [NB_HIST, ...): normalize rows -> bf16 nfb + fp32 norm.
//    Hist blocks are LDS-bound, normalize is HBM-bound -> they overlap.
// ---------------------------------------------------------------------------
__global__ __launch_bounds__(256) void norm_hist_kernel(
        const float* __restrict__ feat,
        const int* __restrict__ dst,
        unsigned int* __restrict__ nfb,
        float* __restrict__ norm,
        int* __restrict__ hist,
        unsigned short* __restrict__ lrank,
        int n_nodes, int n_edges, int epb) {
    __shared__ int lhist[N_NODES_MAX];
    if ((int)blockIdx.x < NB_HIST) {
        int b = blockIdx.x;
        for (int i = threadIdx.x; i < n_nodes; i += 256) lhist[i] = 0;
        __syncthreads();
        int e0 = b * epb;
        int e1 = e0 + epb;
        if (e1 > n_edges) e1 = n_edges;
        for (int e = e0 + (int)threadIdx.x; e < e1; e += 256) {
            int d = dst[e];
            lrank[e] = (unsigned short)atomicAdd(&lhist[d], 1);  // LDS atomic
        }
        __syncthreads();
        for (int i = threadIdx.x; i < n_nodes; i += 256)
            hist[b * n_nodes + i] = lhist[i];
    } else {
        int node = ((int)(blockIdx.x - NB_HIST) * 256 + (int)threadIdx.x) >> 6;
        int lane = threadIdx.x & 63;
        if (node >= n_nodes) return;
        float2 f = ((const float2*)feat)[node * 64 + lane];
        float ss = f.x * f.x + f.y * f.y;
        #pragma unroll
        for (int off = 1; off < 64; off <<= 1)
            ss += __shfl_xor(ss, off, 64);
        float nm = fmaxf(sqrtf(ss), 1e-12f);
        float inv = 1.0f / nm;
        unsigned int lo = f2bf(f.x * inv), hi = f2bf(f.y * inv);
        nfb[node * 64 + lane] = (hi << 16) | lo;
        if (lane == 0) norm[node] = nm;
    }
}

// ---------------------------------------------------------------------------
// 2. One-block scan: hist[b][n] -> (in place) global CSR base per (b,n),
//    plus offsets[n] (exclusive over nodes) and offsets[n_nodes] = total.
//    Thread t owns a contiguous node range; block-wide scan of range sums.
// ---------------------------------------------------------------------------
__global__ __launch_bounds__(1024) void scan2_kernel(int* __restrict__ hist,
                                                     int* __restrict__ offsets,
                                                     int n_nodes) {
    __shared__ int wsum[16];
    int t = threadIdx.x;
    int per = (n_nodes + 1023) >> 10;
    int beg = t * per, end = beg + per;
    if (beg > n_nodes) beg = n_nodes;
    if (end > n_nodes) end = n_nodes;

    int s = 0;
    for (int n = beg; n < end; ++n)
        #pragma unroll 8
        for (int b = 0; b < NB_HIST; ++b)
            s += hist[b * n_nodes + n];

    int lane = t & 63, wid = t >> 6;
    int incl = s;
    #pragma unroll
    for (int off = 1; off < 64; off <<= 1) {
        int v = __shfl_up(incl, off, 64);
        if (lane >= off) incl += v;
    }
    if (lane == 63) wsum[wid] = incl;
    __syncthreads();
    if (t == 0) {
        int run = 0;
        #pragma unroll
        for (int w = 0; w < 16; ++w) { int v = wsum[w]; wsum[w] = run; run += v; }
    }
    __syncthreads();
    int tb = wsum[wid] + (incl - s);   // exclusive prefix for this thread

    int run = tb;
    for (int n = beg; n < end; ++n) {
        offsets[n] = run;
        #pragma unroll 8
        for (int b = 0; b < NB_HIST; ++b) {
            int i = b * n_nodes + n;
            int h = hist[i];
            hist[i] = run;            // in-place: hist becomes CSR base
            run += h;
        }
    }
    if (t == 1023) offsets[n_nodes] = tb;  // empty range -> tb == grand total
}

// ---------------------------------------------------------------------------
// 3. Scatter (no atomics): pos = base[b][d] + lrank. One packed 4B store:
//    (dst<<16) | src  — dot kernel needs both ids per sorted position.
// ---------------------------------------------------------------------------
__global__ void scatter_kernel(const int* __restrict__ src,
                               const int* __restrict__ dst,
                               const int* __restrict__ base,
                               const unsigned short* __restrict__ lrank,
                               unsigned int* __restrict__ pair_sorted,
                               int n_nodes, int n_edges, int epb) {
    int e = blockIdx.x * blockDim.x + threadIdx.x;
    if (e >= n_edges) return;
    int d = dst[e];
    int b = e / epb;
    int pos = base[b * n_nodes + d] + (int)lrank[e];
    pair_sorted[pos] = ((unsigned int)d << 16) | (unsigned int)src[e];
}

// ---------------------------------------------------------------------------
// 4. Dot over SORTED positions: 8 lanes/edge, bf16 rows. Consecutive
//    positions share dst (avg run 64) -> dst row is L1-hot; e_sorted writes
//    are coalesced. Explicit component FMA (no pointer punning).
// ---------------------------------------------------------------------------
__global__ void dot_sorted_kernel(const unsigned int* __restrict__ nfb,
                                  const unsigned int* __restrict__ pair_sorted,
                                  float* __restrict__ e_sorted,
                                  int n_edges) {
    int gtid = blockIdx.x * blockDim.x + threadIdx.x;
    int g = gtid >> 3;
    int r = threadIdx.x & 7;
    if (g >= n_edges) return;
    unsigned int pair = pair_sorted[g];
    int s = (int)(pair & 0xffffu);
    int d = (int)(pair >> 16);
    const uint4* pa = (const uint4*)(nfb + (size_t)s * 64);
    const uint4* pb = (const uint4*)(nfb + (size_t)d * 64);
    uint4 a0 = pa[r], a1 = pa[r + 8];
    uint4 b0 = pb[r], b1 = pb[r + 8];
    float part = 0.0f;
    part += dot_bf2(a0.x, b0.x);
    part += dot_bf2(a0.y, b0.y);
    part += dot_bf2(a0.z, b0.z);
    part += dot_bf2(a0.w, b0.w);
    part += dot_bf2(a1.x, b1.x);
    part += dot_bf2(a1.y, b1.y);
    part += dot_bf2(a1.z, b1.z);
    part += dot_bf2(a1.w, b1.w);
    #pragma unroll
    for (int off = 1; off < 8; off <<= 1)
        part += __shfl_xor(part, off, 8);
    if (r == 0) e_sorted[g] = part;
}

// ---------------------------------------------------------------------------
// 5. Per-node softmax + aggregation. One wave per node; per 64-edge chunk:
//    coalesced e/pair loads, one max-reduce + one online rescale, parallel
//    exp, then ~6-slot/edge inner loop (2 shuffles + bf16 dword + 2 FMA).
// ---------------------------------------------------------------------------
__global__ void agg_kernel(const unsigned int* __restrict__ nfb,
                           const float* __restrict__ norm,
                           const float* __restrict__ beta,
                           const int* __restrict__ offsets,
                           const unsigned int* __restrict__ pair_sorted,
                           const float* __restrict__ e_sorted,
                           float* __restrict__ out, int n_nodes) {
    int node = (int)(blockIdx.x * blockDim.x + threadIdx.x) >> 6;
    int lane = threadIdx.x & 63;
    if (node >= n_nodes) return;
    int beg = offsets[node];
    int end = offsets[node + 1];
    float b = beta[0];

    float m = -INFINITY, l = 0.0f, ax = 0.0f, ay = 0.0f;

    for (int base = beg; base < end; base += 64) {
        int nb = end - base;
        if (nb > 64) nb = 64;
        int gi = base + lane;
        bool valid = gi < end;
        int idx = valid ? (int)(pair_sorted[gi] & 0xffffu) : 0;
        float ev = valid ? b * e_sorted[gi] : -INFINITY;
        float nv = norm[idx];

        float cm = ev;
        #pragma unroll
        for (int off = 1; off < 64; off <<= 1)
            cm = fmaxf(cm, __shfl_xor(cm, off, 64));
        float m2 = fmaxf(m, cm);
        float scale = expf(m - m2);   // first chunk: exp(-inf) = 0
        ax *= scale; ay *= scale; l *= scale;
        m = m2;

        float pe = expf(ev - m);
        l += pe;
        float pv = pe * nv;

        #pragma unroll 8
        for (int j = 0; j < nb; ++j) {
            float wj = __shfl(pv, j, 64);
            int sj = __shfl(idx, j, 64);
            float2 f = bf2_to_f2(nfb[sj * 64 + lane]);
            ax += wj * f.x;
            ay += wj * f.y;
        }
    }
    #pragma unroll
    for (int off = 1; off < 64; off <<= 1)
        l += __shfl_xor(l, off, 64);
    float invl = (l > 0.0f) ? (1.0f / l) : 0.0f;
    ((float2*)out)[node * 64 + lane] = make_float2(ax * invl, ay * invl);
}

// ---------------------------------------------------------------------------
extern "C" void kernel_launch(void* const* d_in, const int* in_sizes, int n_in,
                              void* d_out, int out_size, void* d_ws, size_t ws_size,
                              hipStream_t stream) {
    const float* feat = (const float*)d_in[0];
    const int* src    = (const int*)d_in[1];
    const int* dst    = (const int*)d_in[2];
    const float* beta = (const float*)d_in[3];
    float* out = (float*)d_out;

    const int n_nodes = in_sizes[0] / D_FEAT;
    const int n_edges = in_sizes[1];
    const int epb = (n_edges + NB_HIST - 1) / NB_HIST;

    char* ws = (char*)d_ws;
    size_t off = 0;
    auto alloc = [&](size_t bytes) -> void* {
        void* p = ws + off;
        off += (bytes + 255) & ~(size_t)255;
        return p;
    };
    unsigned int*   nfb         = (unsigned int*)alloc((size_t)n_nodes * 64 * 4); // 2.56 MB
    float*          norm        = (float*)alloc((size_t)n_nodes * 4);
    int*            hist        = (int*)  alloc((size_t)NB_HIST * n_nodes * 4);   // 2.56 MB
    int*            offsets     = (int*)  alloc((size_t)(n_nodes + 1) * 4);
    unsigned short* lrank       = (unsigned short*)alloc((size_t)n_edges * 2);    // 1.28 MB
    unsigned int*   pair_sorted = (unsigned int*)alloc((size_t)n_edges * 4);      // 2.56 MB
    float*          e_sorted    = (float*)alloc((size_t)n_edges * 4);             // 2.56 MB

    int nb_norm = (n_nodes * 64 + 255) / 256;
    norm_hist_kernel<<<NB_HIST + nb_norm, 256, 0, stream>>>(
        feat, dst, nfb, norm, hist, lrank, n_nodes, n_edges, epb);

    scan2_kernel<<<1, 1024, 0, stream>>>(hist, offsets, n_nodes);

    scatter_kernel<<<(n_edges + 255) / 256, 256, 0, stream>>>(
        src, dst, hist, lrank, pair_sorted, n_nodes, n_edges, epb);

    int ds_blocks = (int)(((size_t)n_edges * 8 + 255) / 256);
    dot_sorted_kernel<<<ds_blocks, 256, 0, stream>>>(
        nfb, pair_sorted, e_sorted, n_edges);

    agg_kernel<<<(n_nodes + 3) / 4, 256, 0, stream>>>(
        nfb, norm, beta, offsets, pair_sorted, e_sorted, out, n_nodes);
}

// Round 8
// 153.066 us; speedup vs baseline: 3.7344x; 3.7344x over previous
//
#include <hip/hip_runtime.h>
#include <math.h>

#define D_FEAT 128
#define NB_HIST 64
#define N_NODES_MAX 10016   // LDS histogram capacity (problem has 10000)

// bf16 helpers -------------------------------------------------------------
__device__ __forceinline__ unsigned short f2bf(float x) {   // round-nearest-even
    unsigned int b = __float_as_uint(x);
    return (unsigned short)((b + 0x7fffu + ((b >> 16) & 1u)) >> 16);
}
__device__ __forceinline__ float2 bf2_to_f2(unsigned int u) {
    return make_float2(__uint_as_float(u << 16), __uint_as_float(u & 0xffff0000u));
}
__device__ __forceinline__ float dot_bf2(unsigned int a, unsigned int b) {
    float2 fa = bf2_to_f2(a), fb = bf2_to_f2(b);
    return fa.x * fb.x + fa.y * fb.y;
}

// ---------------------------------------------------------------------------
// 1. Fused grid:
//    blocks [0, NB_HIST): per-block LDS histogram of dst — NO global atomics.
//      lrank[e] = rank of e within (block, dst); hist[b*n_nodes+n] = count
//      (coalesced dump).
//    blocks [NB_HIST, ...): normalize rows -> bf16 nfb + fp32 norm.
// ---------------------------------------------------------------------------
__global__ __launch_bounds__(256) void norm_hist_kernel(
        const float* __restrict__ feat,
        const int* __restrict__ dst,
        unsigned int* __restrict__ nfb,
        float* __restrict__ norm,
        int* __restrict__ hist,
        unsigned short* __restrict__ lrank,
        int n_nodes, int n_edges, int epb) {
    __shared__ int lhist[N_NODES_MAX];
    if ((int)blockIdx.x < NB_HIST) {
        int b = blockIdx.x;
        for (int i = threadIdx.x; i < n_nodes; i += 256) lhist[i] = 0;
        __syncthreads();
        int e0 = b * epb;
        int e1 = e0 + epb;
        if (e1 > n_edges) e1 = n_edges;
        for (int e = e0 + (int)threadIdx.x; e < e1; e += 256) {
            int d = dst[e];
            lrank[e] = (unsigned short)atomicAdd(&lhist[d], 1);  // LDS atomic
        }
        __syncthreads();
        for (int i = threadIdx.x; i < n_nodes; i += 256)
            hist[b * n_nodes + i] = lhist[i];
    } else {
        int node = ((int)(blockIdx.x - NB_HIST) * 256 + (int)threadIdx.x) >> 6;
        int lane = threadIdx.x & 63;
        if (node >= n_nodes) return;
        float2 f = ((const float2*)feat)[node * 64 + lane];
        float ss = f.x * f.x + f.y * f.y;
        #pragma unroll
        for (int off = 1; off < 64; off <<= 1)
            ss += __shfl_xor(ss, off, 64);
        float nm = fmaxf(sqrtf(ss), 1e-12f);
        float inv = 1.0f / nm;
        unsigned int lo = f2bf(f.x * inv), hi = f2bf(f.y * inv);
        nfb[node * 64 + lane] = (hi << 16) | lo;
        if (lane == 0) norm[node] = nm;
    }
}

// ---------------------------------------------------------------------------
// 2a. scanA: one WAVE per node — lane b holds hist[b][node]; 64-lane
//     exclusive scan -> intra-node base per hist block (written in place),
//     total -> cnt[node]. 10000 concurrent waves hide the scattered-access
//     latency that killed round 7's single-block version.
// ---------------------------------------------------------------------------
__global__ __launch_bounds__(256) void scanA_kernel(int* __restrict__ hist,
                                                    int* __restrict__ cnt,
                                                    int n_nodes) {
    int node = (int)(blockIdx.x * blockDim.x + threadIdx.x) >> 6;
    int lane = threadIdx.x & 63;
    if (node >= n_nodes) return;
    int idx = lane * n_nodes + node;
    int v = hist[idx];
    int incl = v;
    #pragma unroll
    for (int off = 1; off < 64; off <<= 1) {
        int t = __shfl_up(incl, off, 64);
        if (lane >= off) incl += t;
    }
    hist[idx] = incl - v;              // exclusive intra-node prefix
    if (lane == 63) cnt[node] = incl;  // node degree
}

// ---------------------------------------------------------------------------
// 2b. scanB: exclusive scan of cnt -> offsets. One 1024-thread block
//     (proven structure from rounds 2-6, ~4 us).
// ---------------------------------------------------------------------------
__global__ __launch_bounds__(1024) void scanB_kernel(const int* __restrict__ cnt,
                                                     int* __restrict__ offsets, int n) {
    __shared__ int wsum[16];
    __shared__ int total;
    int t = threadIdx.x;
    const int per = (n + 1023) >> 10;
    int beg = t * per;
    int end = beg + per;
    if (beg > n) beg = n;
    if (end > n) end = n;
    int local[16];
    int s = 0;
    for (int i = beg; i < end; ++i) { int v = cnt[i]; local[i - beg] = v; s += v; }
    int lane = t & 63, wid = t >> 6;
    int incl = s;
    #pragma unroll
    for (int off = 1; off < 64; off <<= 1) {
        int v = __shfl_up(incl, off, 64);
        if (lane >= off) incl += v;
    }
    if (lane == 63) wsum[wid] = incl;
    __syncthreads();
    if (t == 0) {
        int run = 0;
        #pragma unroll
        for (int w = 0; w < 16; ++w) { int v = wsum[w]; wsum[w] = run; run += v; }
        total = run;
    }
    __syncthreads();
    int base = wsum[wid] + (incl - s);
    for (int i = beg; i < end; ++i) { offsets[i] = base; base += local[i - beg]; }
    if (t == 0) offsets[n] = total;
}

// ---------------------------------------------------------------------------
// 3. Scatter (no atomics): pos = offsets[d] + hist[b][d] + lrank[e].
//    One packed 4B store: (dst<<16) | src.
// ---------------------------------------------------------------------------
__global__ void scatter_kernel(const int* __restrict__ src,
                               const int* __restrict__ dst,
                               const int* __restrict__ offsets,
                               const int* __restrict__ hist,
                               const unsigned short* __restrict__ lrank,
                               unsigned int* __restrict__ pair_sorted,
                               int n_nodes, int n_edges, int epb) {
    int e = blockIdx.x * blockDim.x + threadIdx.x;
    if (e >= n_edges) return;
    int d = dst[e];
    int b = e / epb;
    int pos = offsets[d] + hist[b * n_nodes + d] + (int)lrank[e];
    pair_sorted[pos] = ((unsigned int)d << 16) | (unsigned int)src[e];
}

// ---------------------------------------------------------------------------
// 4. Dot over SORTED positions: 8 lanes/edge, bf16 rows. Consecutive
//    positions share dst (avg run 64) -> dst row is L1-hot; e_sorted writes
//    coalesced. Explicit component FMA (no pointer punning).
// ---------------------------------------------------------------------------
__global__ void dot_sorted_kernel(const unsigned int* __restrict__ nfb,
                                  const unsigned int* __restrict__ pair_sorted,
                                  float* __restrict__ e_sorted,
                                  int n_edges) {
    int gtid = blockIdx.x * blockDim.x + threadIdx.x;
    int g = gtid >> 3;
    int r = threadIdx.x & 7;
    if (g >= n_edges) return;
    unsigned int pair = pair_sorted[g];
    int s = (int)(pair & 0xffffu);
    int d = (int)(pair >> 16);
    const uint4* pa = (const uint4*)(nfb + (size_t)s * 64);
    const uint4* pb = (const uint4*)(nfb + (size_t)d * 64);
    uint4 a0 = pa[r], a1 = pa[r + 8];
    uint4 b0 = pb[r], b1 = pb[r + 8];
    float part = 0.0f;
    part += dot_bf2(a0.x, b0.x);
    part += dot_bf2(a0.y, b0.y);
    part += dot_bf2(a0.z, b0.z);
    part += dot_bf2(a0.w, b0.w);
    part += dot_bf2(a1.x, b1.x);
    part += dot_bf2(a1.y, b1.y);
    part += dot_bf2(a1.z, b1.z);
    part += dot_bf2(a1.w, b1.w);
    #pragma unroll
    for (int off = 1; off < 8; off <<= 1)
        part += __shfl_xor(part, off, 8);
    if (r == 0) e_sorted[g] = part;
}

// ---------------------------------------------------------------------------
// 5. Per-node softmax + aggregation. One wave per node; per 64-edge chunk:
//    coalesced e/pair loads, one max-reduce + one online rescale, parallel
//    exp, then ~6-slot/edge inner loop (2 shuffles + bf16 dword + 2 FMA).
// ---------------------------------------------------------------------------
__global__ void agg_kernel(const unsigned int* __restrict__ nfb,
                           const float* __restrict__ norm,
                           const float* __restrict__ beta,
                           const int* __restrict__ offsets,
                           const unsigned int* __restrict__ pair_sorted,
                           const float* __restrict__ e_sorted,
                           float* __restrict__ out, int n_nodes) {
    int node = (int)(blockIdx.x * blockDim.x + threadIdx.x) >> 6;
    int lane = threadIdx.x & 63;
    if (node >= n_nodes) return;
    int beg = offsets[node];
    int end = offsets[node + 1];
    float b = beta[0];

    float m = -INFINITY, l = 0.0f, ax = 0.0f, ay = 0.0f;

    for (int base = beg; base < end; base += 64) {
        int nb = end - base;
        if (nb > 64) nb = 64;
        int gi = base + lane;
        bool valid = gi < end;
        int idx = valid ? (int)(pair_sorted[gi] & 0xffffu) : 0;
        float ev = valid ? b * e_sorted[gi] : -INFINITY;
        float nv = norm[idx];

        float cm = ev;
        #pragma unroll
        for (int off = 1; off < 64; off <<= 1)
            cm = fmaxf(cm, __shfl_xor(cm, off, 64));
        float m2 = fmaxf(m, cm);
        float scale = expf(m - m2);   // first chunk: exp(-inf) = 0
        ax *= scale; ay *= scale; l *= scale;
        m = m2;

        float pe = expf(ev - m);
        l += pe;
        float pv = pe * nv;

        #pragma unroll 8
        for (int j = 0; j < nb; ++j) {
            float wj = __shfl(pv, j, 64);
            int sj = __shfl(idx, j, 64);
            float2 f = bf2_to_f2(nfb[sj * 64 + lane]);
            ax += wj * f.x;
            ay += wj * f.y;
        }
    }
    #pragma unroll
    for (int off = 1; off < 64; off <<= 1)
        l += __shfl_xor(l, off, 64);
    float invl = (l > 0.0f) ? (1.0f / l) : 0.0f;
    ((float2*)out)[node * 64 + lane] = make_float2(ax * invl, ay * invl);
}

// ---------------------------------------------------------------------------
extern "C" void kernel_launch(void* const* d_in, const int* in_sizes, int n_in,
                              void* d_out, int out_size, void* d_ws, size_t ws_size,
                              hipStream_t stream) {
    const float* feat = (const float*)d_in[0];
    const int* src    = (const int*)d_in[1];
    const int* dst    = (const int*)d_in[2];
    const float* beta = (const float*)d_in[3];
    float* out = (float*)d_out;

    const int n_nodes = in_sizes[0] / D_FEAT;
    const int n_edges = in_sizes[1];
    const int epb = (n_edges + NB_HIST - 1) / NB_HIST;

    char* ws = (char*)d_ws;
    size_t off = 0;
    auto alloc = [&](size_t bytes) -> void* {
        void* p = ws + off;
        off += (bytes + 255) & ~(size_t)255;
        return p;
    };
    unsigned int*   nfb         = (unsigned int*)alloc((size_t)n_nodes * 64 * 4); // 2.56 MB
    float*          norm        = (float*)alloc((size_t)n_nodes * 4);
    int*            hist        = (int*)  alloc((size_t)NB_HIST * n_nodes * 4);   // 2.56 MB
    int*            cnt         = (int*)  alloc((size_t)n_nodes * 4);
    int*            offsets     = (int*)  alloc((size_t)(n_nodes + 1) * 4);
    unsigned short* lrank       = (unsigned short*)alloc((size_t)n_edges * 2);    // 1.28 MB
    unsigned int*   pair_sorted = (unsigned int*)alloc((size_t)n_edges * 4);      // 2.56 MB
    float*          e_sorted    = (float*)alloc((size_t)n_edges * 4);             // 2.56 MB

    int nb_norm = (n_nodes * 64 + 255) / 256;
    norm_hist_kernel<<<NB_HIST + nb_norm, 256, 0, stream>>>(
        feat, dst, nfb, norm, hist, lrank, n_nodes, n_edges, epb);

    scanA_kernel<<<(n_nodes + 3) / 4, 256, 0, stream>>>(hist, cnt, n_nodes);

    scanB_kernel<<<1, 1024, 0, stream>>>(cnt, offsets, n_nodes);

    scatter_kernel<<<(n_edges + 255) / 256, 256, 0, stream>>>(
        src, dst, offsets, hist, lrank, pair_sorted, n_nodes, n_edges, epb);

    int ds_blocks = (int)(((size_t)n_edges * 8 + 255) / 256);
    dot_sorted_kernel<<<ds_blocks, 256, 0, stream>>>(
        nfb, pair_sorted, e_sorted, n_edges);

    agg_kernel<<<(n_nodes + 3) / 4, 256, 0, stream>>>(
        nfb, norm, beta, offsets, pair_sorted, e_sorted, out, n_nodes);
}

// Round 9
// 143.986 us; speedup vs baseline: 3.9699x; 1.0631x over previous
//
#include <hip/hip_runtime.h>
#include <math.h>

#define D_FEAT 128
#define NB_HIST 64
#define N_NODES_MAX 10016   // LDS histogram capacity (problem has 10000)

// bf16 helpers -------------------------------------------------------------
__device__ __forceinline__ unsigned short f2bf(float x) {   // round-nearest-even
    unsigned int b = __float_as_uint(x);
    return (unsigned short)((b + 0x7fffu + ((b >> 16) & 1u)) >> 16);
}
__device__ __forceinline__ float2 bf2_to_f2(unsigned int u) {
    return make_float2(__uint_as_float(u << 16), __uint_as_float(u & 0xffff0000u));
}
__device__ __forceinline__ float dot_bf2(unsigned int a, unsigned int b) {
    float2 fa = bf2_to_f2(a), fb = bf2_to_f2(b);
    return fa.x * fb.x + fa.y * fb.y;
}

// ---------------------------------------------------------------------------
// 1. Fused grid:
//    blocks [0, NB_HIST): per-block LDS histogram of dst — NO global atomics.
//      lrank[e] = rank of e within (block, dst); hist[b*n_nodes+n] = count.
//    blocks [NB_HIST, ...): normalize rows -> bf16 nfb + fp32 norm.
// ---------------------------------------------------------------------------
__global__ __launch_bounds__(256) void norm_hist_kernel(
        const float* __restrict__ feat,
        const int* __restrict__ dst,
        unsigned int* __restrict__ nfb,
        float* __restrict__ norm,
        int* __restrict__ hist,
        unsigned short* __restrict__ lrank,
        int n_nodes, int n_edges, int epb) {
    __shared__ int lhist[N_NODES_MAX];
    if ((int)blockIdx.x < NB_HIST) {
        int b = blockIdx.x;
        for (int i = threadIdx.x; i < n_nodes; i += 256) lhist[i] = 0;
        __syncthreads();
        int e0 = b * epb;
        int e1 = e0 + epb;
        if (e1 > n_edges) e1 = n_edges;
        for (int e = e0 + (int)threadIdx.x; e < e1; e += 256) {
            int d = dst[e];
            lrank[e] = (unsigned short)atomicAdd(&lhist[d], 1);  // LDS atomic
        }
        __syncthreads();
        for (int i = threadIdx.x; i < n_nodes; i += 256)
            hist[b * n_nodes + i] = lhist[i];
    } else {
        int node = ((int)(blockIdx.x - NB_HIST) * 256 + (int)threadIdx.x) >> 6;
        int lane = threadIdx.x & 63;
        if (node >= n_nodes) return;
        float2 f = ((const float2*)feat)[node * 64 + lane];
        float ss = f.x * f.x + f.y * f.y;
        #pragma unroll
        for (int off = 1; off < 64; off <<= 1)
            ss += __shfl_xor(ss, off, 64);
        float nm = fmaxf(sqrtf(ss), 1e-12f);
        float inv = 1.0f / nm;
        unsigned int lo = f2bf(f.x * inv), hi = f2bf(f.y * inv);
        nfb[node * 64 + lane] = (hi << 16) | lo;
        if (lane == 0) norm[node] = nm;
    }
}

// ---------------------------------------------------------------------------
// 2a. scanA: one WAVE per node — lane b holds hist[b][node]; 64-lane
//     exclusive scan -> intra-node base (in place), total -> cnt[node].
// ---------------------------------------------------------------------------
__global__ __launch_bounds__(256) void scanA_kernel(int* __restrict__ hist,
                                                    int* __restrict__ cnt,
                                                    int n_nodes) {
    int node = (int)(blockIdx.x * blockDim.x + threadIdx.x) >> 6;
    int lane = threadIdx.x & 63;
    if (node >= n_nodes) return;
    int idx = lane * n_nodes + node;
    int v = hist[idx];
    int incl = v;
    #pragma unroll
    for (int off = 1; off < 64; off <<= 1) {
        int t = __shfl_up(incl, off, 64);
        if (lane >= off) incl += t;
    }
    hist[idx] = incl - v;              // exclusive intra-node prefix
    if (lane == 63) cnt[node] = incl;  // node degree
}

// ---------------------------------------------------------------------------
// 2b. scanB: exclusive scan of cnt -> offsets. One 1024-thread block.
// ---------------------------------------------------------------------------
__global__ __launch_bounds__(1024) void scanB_kernel(const int* __restrict__ cnt,
                                                     int* __restrict__ offsets, int n) {
    __shared__ int wsum[16];
    __shared__ int total;
    int t = threadIdx.x;
    const int per = (n + 1023) >> 10;
    int beg = t * per;
    int end = beg + per;
    if (beg > n) beg = n;
    if (end > n) end = n;
    int local[16];
    int s = 0;
    for (int i = beg; i < end; ++i) { int v = cnt[i]; local[i - beg] = v; s += v; }
    int lane = t & 63, wid = t >> 6;
    int incl = s;
    #pragma unroll
    for (int off = 1; off < 64; off <<= 1) {
        int v = __shfl_up(incl, off, 64);
        if (lane >= off) incl += v;
    }
    if (lane == 63) wsum[wid] = incl;
    __syncthreads();
    if (t == 0) {
        int run = 0;
        #pragma unroll
        for (int w = 0; w < 16; ++w) { int v = wsum[w]; wsum[w] = run; run += v; }
        total = run;
    }
    __syncthreads();
    int base = wsum[wid] + (incl - s);
    for (int i = beg; i < end; ++i) { offsets[i] = base; base += local[i - beg]; }
    if (t == 0) offsets[n] = total;
}

// ---------------------------------------------------------------------------
// 3. Scatter (no atomics): pos = offsets[d] + hist[b][d] + lrank[e].
//    One packed 4B store: (dst<<16) | src.
// ---------------------------------------------------------------------------
__global__ void scatter_kernel(const int* __restrict__ src,
                               const int* __restrict__ dst,
                               const int* __restrict__ offsets,
                               const int* __restrict__ hist,
                               const unsigned short* __restrict__ lrank,
                               unsigned int* __restrict__ pair_sorted,
                               int n_nodes, int n_edges, int epb) {
    int e = blockIdx.x * blockDim.x + threadIdx.x;
    if (e >= n_edges) return;
    int d = dst[e];
    int b = e / epb;
    int pos = offsets[d] + hist[b * n_nodes + d] + (int)lrank[e];
    pair_sorted[pos] = ((unsigned int)d << 16) | (unsigned int)src[e];
}

// ---------------------------------------------------------------------------
// 4. Dot over SORTED positions: 8 lanes/edge, bf16 rows. Consecutive
//    positions share dst (avg run 64) -> dst row is L1-hot; e_sorted writes
//    coalesced. Explicit component FMA (no pointer punning).
// ---------------------------------------------------------------------------
__global__ void dot_sorted_kernel(const unsigned int* __restrict__ nfb,
                                  const unsigned int* __restrict__ pair_sorted,
                                  float* __restrict__ e_sorted,
                                  int n_edges) {
    int gtid = blockIdx.x * blockDim.x + threadIdx.x;
    int g = gtid >> 3;
    int r = threadIdx.x & 7;
    if (g >= n_edges) return;
    unsigned int pair = pair_sorted[g];
    int s = (int)(pair & 0xffffu);
    int d = (int)(pair >> 16);
    const uint4* pa = (const uint4*)(nfb + (size_t)s * 64);
    const uint4* pb = (const uint4*)(nfb + (size_t)d * 64);
    uint4 a0 = pa[r], a1 = pa[r + 8];
    uint4 b0 = pb[r], b1 = pb[r + 8];
    float part = 0.0f;
    part += dot_bf2(a0.x, b0.x);
    part += dot_bf2(a0.y, b0.y);
    part += dot_bf2(a0.z, b0.z);
    part += dot_bf2(a0.w, b0.w);
    part += dot_bf2(a1.x, b1.x);
    part += dot_bf2(a1.y, b1.y);
    part += dot_bf2(a1.z, b1.z);
    part += dot_bf2(a1.w, b1.w);
    #pragma unroll
    for (int off = 1; off < 8; off <<= 1)
        part += __shfl_xor(part, off, 8);
    if (r == 0) e_sorted[g] = part;
}

// ---------------------------------------------------------------------------
// 5. Per-node softmax + aggregation. One wave per node; per 64-edge chunk:
//    coalesced e/pair loads, one max-reduce + one online rescale, parallel
//    exp. Inner loop processes TWO edges per iteration: half-wave per edge,
//    uint2 (8B) row loads — halves the gather-instruction count vs round 8.
//    Halves merged by shfl_xor(32) at the end; lanes 0-31 write float4.
// ---------------------------------------------------------------------------
__global__ void agg_kernel(const unsigned int* __restrict__ nfb,
                           const float* __restrict__ norm,
                           const float* __restrict__ beta,
                           const int* __restrict__ offsets,
                           const unsigned int* __restrict__ pair_sorted,
                           const float* __restrict__ e_sorted,
                           float* __restrict__ out, int n_nodes) {
    int node = (int)(blockIdx.x * blockDim.x + threadIdx.x) >> 6;
    int lane = threadIdx.x & 63;
    if (node >= n_nodes) return;
    int beg = offsets[node];
    int end = offsets[node + 1];
    float b = beta[0];
    int half = lane >> 5;        // 0: even edge of pair, 1: odd edge
    int hl = lane & 31;          // position within half -> dims 4*hl..4*hl+3

    float m = -INFINITY, l = 0.0f;
    float ax = 0.0f, ay = 0.0f, az = 0.0f, aw = 0.0f;

    for (int base = beg; base < end; base += 64) {
        int nb = end - base;
        if (nb > 64) nb = 64;
        int gi = base + lane;
        bool valid = gi < end;
        int idx = valid ? (int)(pair_sorted[gi] & 0xffffu) : 0;
        float ev = valid ? b * e_sorted[gi] : -INFINITY;
        float nv = norm[idx];

        float cm = ev;
        #pragma unroll
        for (int off = 1; off < 64; off <<= 1)
            cm = fmaxf(cm, __shfl_xor(cm, off, 64));
        float m2 = fmaxf(m, cm);
        float scale = expf(m - m2);   // first chunk: exp(-inf) = 0
        ax *= scale; ay *= scale; az *= scale; aw *= scale; l *= scale;
        m = m2;

        float pe = expf(ev - m);      // 0 for invalid lanes
        l += pe;
        float pv = pe * nv;           // pv == 0 for invalid lanes -> odd-tail safe

        #pragma unroll 8
        for (int j = 0; j < nb; j += 2) {
            int jj = j + half;                       // lanes 0-31: j, 32-63: j+1
            float wj = __shfl(pv, jj, 64);           // 0 if jj == nb (odd tail)
            int   sj = __shfl(idx, jj, 64);
            uint2 u = ((const uint2*)nfb)[(size_t)sj * 32 + hl];
            float2 f0 = bf2_to_f2(u.x);
            float2 f1 = bf2_to_f2(u.y);
            ax += wj * f0.x;
            ay += wj * f0.y;
            az += wj * f1.x;
            aw += wj * f1.y;
        }
    }
    #pragma unroll
    for (int off = 1; off < 64; off <<= 1)
        l += __shfl_xor(l, off, 64);
    // merge the two half-wave accumulator sets (same dims in both halves)
    ax += __shfl_xor(ax, 32, 64);
    ay += __shfl_xor(ay, 32, 64);
    az += __shfl_xor(az, 32, 64);
    aw += __shfl_xor(aw, 32, 64);
    float invl = (l > 0.0f) ? (1.0f / l) : 0.0f;
    if (half == 0)
        ((float4*)out)[(size_t)node * 32 + hl] =
            make_float4(ax * invl, ay * invl, az * invl, aw * invl);
}

// ---------------------------------------------------------------------------
extern "C" void kernel_launch(void* const* d_in, const int* in_sizes, int n_in,
                              void* d_out, int out_size, void* d_ws, size_t ws_size,
                              hipStream_t stream) {
    const float* feat = (const float*)d_in[0];
    const int* src    = (const int*)d_in[1];
    const int* dst    = (const int*)d_in[2];
    const float* beta = (const float*)d_in[3];
    float* out = (float*)d_out;

    const int n_nodes = in_sizes[0] / D_FEAT;
    const int n_edges = in_sizes[1];
    const int epb = (n_edges + NB_HIST - 1) / NB_HIST;

    char* ws = (char*)d_ws;
    size_t off = 0;
    auto alloc = [&](size_t bytes) -> void* {
        void* p = ws + off;
        off += (bytes + 255) & ~(size_t)255;
        return p;
    };
    unsigned int*   nfb         = (unsigned int*)alloc((size_t)n_nodes * 64 * 4); // 2.56 MB
    float*          norm        = (float*)alloc((size_t)n_nodes * 4);
    int*            hist        = (int*)  alloc((size_t)NB_HIST * n_nodes * 4);   // 2.56 MB
    int*            cnt         = (int*)  alloc((size_t)n_nodes * 4);
    int*            offsets     = (int*)  alloc((size_t)(n_nodes + 1) * 4);
    unsigned short* lrank       = (unsigned short*)alloc((size_t)n_edges * 2);    // 1.28 MB
    unsigned int*   pair_sorted = (unsigned int*)alloc((size_t)n_edges * 4);      // 2.56 MB
    float*          e_sorted    = (float*)alloc((size_t)n_edges * 4);             // 2.56 MB

    int nb_norm = (n_nodes * 64 + 255) / 256;
    norm_hist_kernel<<<NB_HIST + nb_norm, 256, 0, stream>>>(
        feat, dst, nfb, norm, hist, lrank, n_nodes, n_edges, epb);

    scanA_kernel<<<(n_nodes + 3) / 4, 256, 0, stream>>>(hist, cnt, n_nodes);

    scanB_kernel<<<1, 1024, 0, stream>>>(cnt, offsets, n_nodes);

    scatter_kernel<<<(n_edges + 255) / 256, 256, 0, stream>>>(
        src, dst, offsets, hist, lrank, pair_sorted, n_nodes, n_edges, epb);

    int ds_blocks = (int)(((size_t)n_edges * 8 + 255) / 256);
    dot_sorted_kernel<<<ds_blocks, 256, 0, stream>>>(
        nfb, pair_sorted, e_sorted, n_edges);

    agg_kernel<<<(n_nodes + 3) / 4, 256, 0, stream>>>(
        nfb, norm, beta, offsets, pair_sorted, e_sorted, out, n_nodes);
}

// Round 10
// 141.730 us; speedup vs baseline: 4.0331x; 1.0159x over previous
//
#include <hip/hip_runtime.h>
#include <math.h>

#define D_FEAT 128
#define NB_HIST 128
#define N_NODES_MAX 10016   // LDS histogram capacity (problem has 10000)

// bf16 helpers -------------------------------------------------------------
__device__ __forceinline__ unsigned short f2bf(float x) {   // round-nearest-even
    unsigned int b = __float_as_uint(x);
    return (unsigned short)((b + 0x7fffu + ((b >> 16) & 1u)) >> 16);
}
__device__ __forceinline__ float2 bf2_to_f2(unsigned int u) {
    return make_float2(__uint_as_float(u << 16), __uint_as_float(u & 0xffff0000u));
}
__device__ __forceinline__ float dot_bf2(unsigned int a, unsigned int b) {
    float2 fa = bf2_to_f2(a), fb = bf2_to_f2(b);
    return fa.x * fb.x + fa.y * fb.y;
}

// ---------------------------------------------------------------------------
// 1. Fused grid:
//    blocks [0, NB_HIST): per-block LDS histogram of dst — NO global atomics.
//      lrank[e] = rank of e within (block, dst); hist[b*n_nodes+n] = count.
//      128 blocks -> each handles only 5000 edges (~20 serial iters/thread).
//    blocks [NB_HIST, ...): normalize rows -> bf16 nfb + fp32 norm.
// ---------------------------------------------------------------------------
__global__ __launch_bounds__(256) void norm_hist_kernel(
        const float* __restrict__ feat,
        const int* __restrict__ dst,
        unsigned int* __restrict__ nfb,
        float* __restrict__ norm,
        int* __restrict__ hist,
        unsigned short* __restrict__ lrank,
        int n_nodes, int n_edges, int epb) {
    __shared__ int lhist[N_NODES_MAX];
    if ((int)blockIdx.x < NB_HIST) {
        int b = blockIdx.x;
        for (int i = threadIdx.x; i < n_nodes; i += 256) lhist[i] = 0;
        __syncthreads();
        int e0 = b * epb;
        int e1 = e0 + epb;
        if (e1 > n_edges) e1 = n_edges;
        for (int e = e0 + (int)threadIdx.x; e < e1; e += 256) {
            int d = dst[e];
            lrank[e] = (unsigned short)atomicAdd(&lhist[d], 1);  // LDS atomic
        }
        __syncthreads();
        for (int i = threadIdx.x; i < n_nodes; i += 256)
            hist[b * n_nodes + i] = lhist[i];
    } else {
        int node = ((int)(blockIdx.x - NB_HIST) * 256 + (int)threadIdx.x) >> 6;
        int lane = threadIdx.x & 63;
        if (node >= n_nodes) return;
        float2 f = ((const float2*)feat)[node * 64 + lane];
        float ss = f.x * f.x + f.y * f.y;
        #pragma unroll
        for (int off = 1; off < 64; off <<= 1)
            ss += __shfl_xor(ss, off, 64);
        float nm = fmaxf(sqrtf(ss), 1e-12f);
        float inv = 1.0f / nm;
        unsigned int lo = f2bf(f.x * inv), hi = f2bf(f.y * inv);
        nfb[node * 64 + lane] = (hi << 16) | lo;
        if (lane == 0) norm[node] = nm;
    }
}

// ---------------------------------------------------------------------------
// 2a. scanA: one WAVE per node — lane b holds hist[b][node] and
//     hist[64+b][node]; two 64-lane scans with carry -> exclusive intra-node
//     base per hist block (in place), total -> cnt[node].
// ---------------------------------------------------------------------------
__global__ __launch_bounds__(256) void scanA_kernel(int* __restrict__ hist,
                                                    int* __restrict__ cnt,
                                                    int n_nodes) {
    int node = (int)(blockIdx.x * blockDim.x + threadIdx.x) >> 6;
    int lane = threadIdx.x & 63;
    if (node >= n_nodes) return;
    int idx0 = lane * n_nodes + node;
    int idx1 = (64 + lane) * n_nodes + node;
    int v0 = hist[idx0];
    int v1 = hist[idx1];
    int incl0 = v0;
    #pragma unroll
    for (int off = 1; off < 64; off <<= 1) {
        int t = __shfl_up(incl0, off, 64);
        if (lane >= off) incl0 += t;
    }
    int tot0 = __shfl(incl0, 63, 64);
    int incl1 = v1;
    #pragma unroll
    for (int off = 1; off < 64; off <<= 1) {
        int t = __shfl_up(incl1, off, 64);
        if (lane >= off) incl1 += t;
    }
    hist[idx0] = incl0 - v0;                 // exclusive prefix, b = lane
    hist[idx1] = tot0 + incl1 - v1;          // exclusive prefix, b = 64+lane
    if (lane == 63) cnt[node] = tot0 + incl1;  // node degree
}

// ---------------------------------------------------------------------------
// 2b. scanB: exclusive scan of cnt -> offsets. One 1024-thread block.
// ---------------------------------------------------------------------------
__global__ __launch_bounds__(1024) void scanB_kernel(const int* __restrict__ cnt,
                                                     int* __restrict__ offsets, int n) {
    __shared__ int wsum[16];
    __shared__ int total;
    int t = threadIdx.x;
    const int per = (n + 1023) >> 10;
    int beg = t * per;
    int end = beg + per;
    if (beg > n) beg = n;
    if (end > n) end = n;
    int local[16];
    int s = 0;
    for (int i = beg; i < end; ++i) { int v = cnt[i]; local[i - beg] = v; s += v; }
    int lane = t & 63, wid = t >> 6;
    int incl = s;
    #pragma unroll
    for (int off = 1; off < 64; off <<= 1) {
        int v = __shfl_up(incl, off, 64);
        if (lane >= off) incl += v;
    }
    if (lane == 63) wsum[wid] = incl;
    __syncthreads();
    if (t == 0) {
        int run = 0;
        #pragma unroll
        for (int w = 0; w < 16; ++w) { int v = wsum[w]; wsum[w] = run; run += v; }
        total = run;
    }
    __syncthreads();
    int base = wsum[wid] + (incl - s);
    for (int i = beg; i < end; ++i) { offsets[i] = base; base += local[i - beg]; }
    if (t == 0) offsets[n] = total;
}

// ---------------------------------------------------------------------------
// 3. Scatter (no atomics): pos = offsets[d] + hist[b][d] + lrank[e].
//    One packed 4B store: (dst<<16) | src.
// ---------------------------------------------------------------------------
__global__ void scatter_kernel(const int* __restrict__ src,
                               const int* __restrict__ dst,
                               const int* __restrict__ offsets,
                               const int* __restrict__ hist,
                               const unsigned short* __restrict__ lrank,
                               unsigned int* __restrict__ pair_sorted,
                               int n_nodes, int n_edges, int epb) {
    int e = blockIdx.x * blockDim.x + threadIdx.x;
    if (e >= n_edges) return;
    int d = dst[e];
    int b = e / epb;
    int pos = offsets[d] + hist[b * n_nodes + d] + (int)lrank[e];
    pair_sorted[pos] = ((unsigned int)d << 16) | (unsigned int)src[e];
}

// ---------------------------------------------------------------------------
// 4. Dot over SORTED positions: 8 lanes/edge, bf16 rows. Consecutive
//    positions share dst (avg run 64) -> dst row is L1-hot; e_sorted writes
//    coalesced. Explicit component FMA (no pointer punning).
// ---------------------------------------------------------------------------
__global__ void dot_sorted_kernel(const unsigned int* __restrict__ nfb,
                                  const unsigned int* __restrict__ pair_sorted,
                                  float* __restrict__ e_sorted,
                                  int n_edges) {
    int gtid = blockIdx.x * blockDim.x + threadIdx.x;
    int g = gtid >> 3;
    int r = threadIdx.x & 7;
    if (g >= n_edges) return;
    unsigned int pair = pair_sorted[g];
    int s = (int)(pair & 0xffffu);
    int d = (int)(pair >> 16);
    const uint4* pa = (const uint4*)(nfb + (size_t)s * 64);
    const uint4* pb = (const uint4*)(nfb + (size_t)d * 64);
    uint4 a0 = pa[r], a1 = pa[r + 8];
    uint4 b0 = pb[r], b1 = pb[r + 8];
    float part = 0.0f;
    part += dot_bf2(a0.x, b0.x);
    part += dot_bf2(a0.y, b0.y);
    part += dot_bf2(a0.z, b0.z);
    part += dot_bf2(a0.w, b0.w);
    part += dot_bf2(a1.x, b1.x);
    part += dot_bf2(a1.y, b1.y);
    part += dot_bf2(a1.z, b1.z);
    part += dot_bf2(a1.w, b1.w);
    #pragma unroll
    for (int off = 1; off < 8; off <<= 1)
        part += __shfl_xor(part, off, 8);
    if (r == 0) e_sorted[g] = part;
}

// ---------------------------------------------------------------------------
// 5. Per-node softmax + aggregation. One wave per node; per 64-edge chunk:
//    coalesced e/pair loads, one max-reduce + one online rescale, parallel
//    exp. Inner loop: QUARTER-wave (16 lanes) per edge, 4 edges/iteration,
//    uint4 (16B/lane) row loads — one gather instruction per 4 edges.
//    Quarters merged by shfl_xor(16,32); lanes 0-15 write two float4s.
// ---------------------------------------------------------------------------
__global__ void agg_kernel(const unsigned int* __restrict__ nfb,
                           const float* __restrict__ norm,
                           const float* __restrict__ beta,
                           const int* __restrict__ offsets,
                           const unsigned int* __restrict__ pair_sorted,
                           const float* __restrict__ e_sorted,
                           float* __restrict__ out, int n_nodes) {
    int node = (int)(blockIdx.x * blockDim.x + threadIdx.x) >> 6;
    int lane = threadIdx.x & 63;
    if (node >= n_nodes) return;
    int beg = offsets[node];
    int end = offsets[node + 1];
    float b = beta[0];
    int q  = lane >> 4;          // quarter id 0..3 -> edge j+q
    int ql = lane & 15;          // dims 8*ql .. 8*ql+7

    float m = -INFINITY, l = 0.0f;
    float a0 = 0.f, a1 = 0.f, a2 = 0.f, a3 = 0.f;
    float a4 = 0.f, a5 = 0.f, a6 = 0.f, a7 = 0.f;

    for (int base = beg; base < end; base += 64) {
        int nb = end - base;
        if (nb > 64) nb = 64;
        int gi = base + lane;
        bool valid = gi < end;
        int idx = valid ? (int)(pair_sorted[gi] & 0xffffu) : 0;
        float ev = valid ? b * e_sorted[gi] : -INFINITY;
        float nv = norm[idx];

        float cm = ev;
        #pragma unroll
        for (int off = 1; off < 64; off <<= 1)
            cm = fmaxf(cm, __shfl_xor(cm, off, 64));
        float m2 = fmaxf(m, cm);
        float scale = expf(m - m2);   // first chunk: exp(-inf) = 0
        a0 *= scale; a1 *= scale; a2 *= scale; a3 *= scale;
        a4 *= scale; a5 *= scale; a6 *= scale; a7 *= scale;
        l *= scale;
        m = m2;

        float pe = expf(ev - m);      // 0 for invalid lanes
        l += pe;
        float pv = pe * nv;           // 0 for invalid lanes -> tail-safe

        #pragma unroll 4
        for (int j = 0; j < nb; j += 4) {
            int jj = j + q;                          // quarter q takes edge j+q
            float wj = __shfl(pv, jj, 64);           // 0 if jj >= nb (tail)
            int   sj = __shfl(idx, jj, 64);
            uint4 u = ((const uint4*)nfb)[(size_t)sj * 16 + ql];
            float2 f0 = bf2_to_f2(u.x);
            float2 f1 = bf2_to_f2(u.y);
            float2 f2 = bf2_to_f2(u.z);
            float2 f3 = bf2_to_f2(u.w);
            a0 += wj * f0.x;  a1 += wj * f0.y;
            a2 += wj * f1.x;  a3 += wj * f1.y;
            a4 += wj * f2.x;  a5 += wj * f2.y;
            a6 += wj * f3.x;  a7 += wj * f3.y;
        }
    }
    #pragma unroll
    for (int off = 1; off < 64; off <<= 1)
        l += __shfl_xor(l, off, 64);
    // merge the four quarter-wave accumulator sets (same dims in all quarters)
    a0 += __shfl_xor(a0, 16, 64); a0 += __shfl_xor(a0, 32, 64);
    a1 += __shfl_xor(a1, 16, 64); a1 += __shfl_xor(a1, 32, 64);
    a2 += __shfl_xor(a2, 16, 64); a2 += __shfl_xor(a2, 32, 64);
    a3 += __shfl_xor(a3, 16, 64); a3 += __shfl_xor(a3, 32, 64);
    a4 += __shfl_xor(a4, 16, 64); a4 += __shfl_xor(a4, 32, 64);
    a5 += __shfl_xor(a5, 16, 64); a5 += __shfl_xor(a5, 32, 64);
    a6 += __shfl_xor(a6, 16, 64); a6 += __shfl_xor(a6, 32, 64);
    a7 += __shfl_xor(a7, 16, 64); a7 += __shfl_xor(a7, 32, 64);
    float invl = (l > 0.0f) ? (1.0f / l) : 0.0f;
    if (q == 0) {
        float4* o = (float4*)out + (size_t)node * 32 + ql * 2;
        o[0] = make_float4(a0 * invl, a1 * invl, a2 * invl, a3 * invl);
        o[1] = make_float4(a4 * invl, a5 * invl, a6 * invl, a7 * invl);
    }
}

// ---------------------------------------------------------------------------
extern "C" void kernel_launch(void* const* d_in, const int* in_sizes, int n_in,
                              void* d_out, int out_size, void* d_ws, size_t ws_size,
                              hipStream_t stream) {
    const float* feat = (const float*)d_in[0];
    const int* src    = (const int*)d_in[1];
    const int* dst    = (const int*)d_in[2];
    const float* beta = (const float*)d_in[3];
    float* out = (float*)d_out;

    const int n_nodes = in_sizes[0] / D_FEAT;
    const int n_edges = in_sizes[1];
    const int epb = (n_edges + NB_HIST - 1) / NB_HIST;

    char* ws = (char*)d_ws;
    size_t off = 0;
    auto alloc = [&](size_t bytes) -> void* {
        void* p = ws + off;
        off += (bytes + 255) & ~(size_t)255;
        return p;
    };
    unsigned int*   nfb         = (unsigned int*)alloc((size_t)n_nodes * 64 * 4); // 2.56 MB
    float*          norm        = (float*)alloc((size_t)n_nodes * 4);
    int*            hist        = (int*)  alloc((size_t)NB_HIST * n_nodes * 4);   // 5.12 MB
    int*            cnt         = (int*)  alloc((size_t)n_nodes * 4);
    int*            offsets     = (int*)  alloc((size_t)(n_nodes + 1) * 4);
    unsigned short* lrank       = (unsigned short*)alloc((size_t)n_edges * 2);    // 1.28 MB
    unsigned int*   pair_sorted = (unsigned int*)alloc((size_t)n_edges * 4);      // 2.56 MB
    float*          e_sorted    = (float*)alloc((size_t)n_edges * 4);             // 2.56 MB

    int nb_norm = (n_nodes * 64 + 255) / 256;
    norm_hist_kernel<<<NB_HIST + nb_norm, 256, 0, stream>>>(
        feat, dst, nfb, norm, hist, lrank, n_nodes, n_edges, epb);

    scanA_kernel<<<(n_nodes + 3) / 4, 256, 0, stream>>>(hist, cnt, n_nodes);

    scanB_kernel<<<1, 1024, 0, stream>>>(cnt, offsets, n_nodes);

    scatter_kernel<<<(n_edges + 255) / 256, 256, 0, stream>>>(
        src, dst, offsets, hist, lrank, pair_sorted, n_nodes, n_edges, epb);

    int ds_blocks = (int)(((size_t)n_edges * 8 + 255) / 256);
    dot_sorted_kernel<<<ds_blocks, 256, 0, stream>>>(
        nfb, pair_sorted, e_sorted, n_edges);

    agg_kernel<<<(n_nodes + 3) / 4, 256, 0, stream>>>(
        nfb, norm, beta, offsets, pair_sorted, e_sorted, out, n_nodes);
}

// Round 11
// 140.142 us; speedup vs baseline: 4.0788x; 1.0113x over previous
//
#include <hip/hip_runtime.h>
#include <math.h>

#define D_FEAT 128
#define NB_HIST 128
#define N_NODES_MAX 10016   // LDS histogram capacity (problem has 10000)

// bf16 helpers -------------------------------------------------------------
__device__ __forceinline__ unsigned short f2bf(float x) {   // round-nearest-even
    unsigned int b = __float_as_uint(x);
    return (unsigned short)((b + 0x7fffu + ((b >> 16) & 1u)) >> 16);
}
__device__ __forceinline__ float2 bf2_to_f2(unsigned int u) {
    return make_float2(__uint_as_float(u << 16), __uint_as_float(u & 0xffff0000u));
}

// ---------------------------------------------------------------------------
// 1. Fused grid:
//    blocks [0, NB_HIST): per-block LDS histogram of dst — NO global atomics.
//      lrank[e] = rank of e within (block, dst); hist[b*n_nodes+n] = count.
//    blocks [NB_HIST, ...): normalize rows -> bf16 nfb + fp32 norm.
// ---------------------------------------------------------------------------
__global__ __launch_bounds__(256) void norm_hist_kernel(
        const float* __restrict__ feat,
        const int* __restrict__ dst,
        unsigned int* __restrict__ nfb,
        float* __restrict__ norm,
        int* __restrict__ hist,
        unsigned short* __restrict__ lrank,
        int n_nodes, int n_edges, int epb) {
    __shared__ int lhist[N_NODES_MAX];
    if ((int)blockIdx.x < NB_HIST) {
        int b = blockIdx.x;
        for (int i = threadIdx.x; i < n_nodes; i += 256) lhist[i] = 0;
        __syncthreads();
        int e0 = b * epb;
        int e1 = e0 + epb;
        if (e1 > n_edges) e1 = n_edges;
        for (int e = e0 + (int)threadIdx.x; e < e1; e += 256) {
            int d = dst[e];
            lrank[e] = (unsigned short)atomicAdd(&lhist[d], 1);  // LDS atomic
        }
        __syncthreads();
        for (int i = threadIdx.x; i < n_nodes; i += 256)
            hist[b * n_nodes + i] = lhist[i];
    } else {
        int node = ((int)(blockIdx.x - NB_HIST) * 256 + (int)threadIdx.x) >> 6;
        int lane = threadIdx.x & 63;
        if (node >= n_nodes) return;
        float2 f = ((const float2*)feat)[node * 64 + lane];
        float ss = f.x * f.x + f.y * f.y;
        #pragma unroll
        for (int off = 1; off < 64; off <<= 1)
            ss += __shfl_xor(ss, off, 64);
        float nm = fmaxf(sqrtf(ss), 1e-12f);
        float inv = 1.0f / nm;
        unsigned int lo = f2bf(f.x * inv), hi = f2bf(f.y * inv);
        nfb[node * 64 + lane] = (hi << 16) | lo;
        if (lane == 0) norm[node] = nm;
    }
}

// ---------------------------------------------------------------------------
// 2a. scanA: one WAVE per node — lane b holds hist[b][node] and
//     hist[64+b][node]; two 64-lane scans with carry -> exclusive intra-node
//     base per hist block (in place), total -> cnt[node].
// ---------------------------------------------------------------------------
__global__ __launch_bounds__(256) void scanA_kernel(int* __restrict__ hist,
                                                    int* __restrict__ cnt,
                                                    int n_nodes) {
    int node = (int)(blockIdx.x * blockDim.x + threadIdx.x) >> 6;
    int lane = threadIdx.x & 63;
    if (node >= n_nodes) return;
    int idx0 = lane * n_nodes + node;
    int idx1 = (64 + lane) * n_nodes + node;
    int v0 = hist[idx0];
    int v1 = hist[idx1];
    int incl0 = v0;
    #pragma unroll
    for (int off = 1; off < 64; off <<= 1) {
        int t = __shfl_up(incl0, off, 64);
        if (lane >= off) incl0 += t;
    }
    int tot0 = __shfl(incl0, 63, 64);
    int incl1 = v1;
    #pragma unroll
    for (int off = 1; off < 64; off <<= 1) {
        int t = __shfl_up(incl1, off, 64);
        if (lane >= off) incl1 += t;
    }
    hist[idx0] = incl0 - v0;                 // exclusive prefix, b = lane
    hist[idx1] = tot0 + incl1 - v1;          // exclusive prefix, b = 64+lane
    if (lane == 63) cnt[node] = tot0 + incl1;  // node degree
}

// ---------------------------------------------------------------------------
// 2b. scanB: exclusive scan of cnt -> offsets. One 1024-thread block.
// ---------------------------------------------------------------------------
__global__ __launch_bounds__(1024) void scanB_kernel(const int* __restrict__ cnt,
                                                     int* __restrict__ offsets, int n) {
    __shared__ int wsum[16];
    __shared__ int total;
    int t = threadIdx.x;
    const int per = (n + 1023) >> 10;
    int beg = t * per;
    int end = beg + per;
    if (beg > n) beg = n;
    if (end > n) end = n;
    int local[16];
    int s = 0;
    for (int i = beg; i < end; ++i) { int v = cnt[i]; local[i - beg] = v; s += v; }
    int lane = t & 63, wid = t >> 6;
    int incl = s;
    #pragma unroll
    for (int off = 1; off < 64; off <<= 1) {
        int v = __shfl_up(incl, off, 64);
        if (lane >= off) incl += v;
    }
    if (lane == 63) wsum[wid] = incl;
    __syncthreads();
    if (t == 0) {
        int run = 0;
        #pragma unroll
        for (int w = 0; w < 16; ++w) { int v = wsum[w]; wsum[w] = run; run += v; }
        total = run;
    }
    __syncthreads();
    int base = wsum[wid] + (incl - s);
    for (int i = beg; i < end; ++i) { offsets[i] = base; base += local[i - beg]; }
    if (t == 0) offsets[n] = total;
}

// ---------------------------------------------------------------------------
// 3. Scatter (no atomics): pos = offsets[d] + hist[b][d] + lrank[e].
//    One packed 4B store: (dst<<16) | src.
// ---------------------------------------------------------------------------
__global__ void scatter_kernel(const int* __restrict__ src,
                               const int* __restrict__ dst,
                               const int* __restrict__ offsets,
                               const int* __restrict__ hist,
                               const unsigned short* __restrict__ lrank,
                               unsigned int* __restrict__ pair_sorted,
                               int n_nodes, int n_edges, int epb) {
    int e = blockIdx.x * blockDim.x + threadIdx.x;
    if (e >= n_edges) return;
    int d = dst[e];
    int b = e / epb;
    int pos = offsets[d] + hist[b * n_nodes + d] + (int)lrank[e];
    pair_sorted[pos] = ((unsigned int)d << 16) | (unsigned int)src[e];
}

// ---------------------------------------------------------------------------
// 4. FUSED dot + softmax + aggregation. One wave per node.
//    Per 64-edge chunk:
//      pass A: quarter-wave parallel dots — each 16-lane quarter holds the
//              full dst row (uint4/lane), computes one edge's dot (8 FMA) +
//              4-step intra-quarter reduce; 4 edges in flight per iteration.
//              Cross-quarter __shfl deposits edge i's dot into lane i.
//              (Round-4's fused dot was a SERIALIZED full-wave reduce/edge —
//               that mistake is not repeated here.)
//      chunk softmax: one max-reduce + one online rescale, parallel exp.
//      pass B: same rows re-gathered (L1-hot from pass A), weighted by p.
//    No e_sorted round trip; dot kernel eliminated.
// ---------------------------------------------------------------------------
__global__ void agg_kernel(const unsigned int* __restrict__ nfb,
                           const float* __restrict__ norm,
                           const float* __restrict__ beta,
                           const int* __restrict__ offsets,
                           const unsigned int* __restrict__ pair_sorted,
                           float* __restrict__ out, int n_nodes) {
    int node = (int)(blockIdx.x * blockDim.x + threadIdx.x) >> 6;
    int lane = threadIdx.x & 63;
    if (node >= n_nodes) return;
    int beg = offsets[node];
    int end = offsets[node + 1];
    float b = beta[0];
    int q  = lane >> 4;          // quarter id 0..3
    int ql = lane & 15;          // dims 8*ql .. 8*ql+7

    // dst row: each quarter holds the full 128-dim row (16 lanes x uint4)
    uint4 du = ((const uint4*)nfb)[(size_t)node * 16 + ql];
    float2 d0 = bf2_to_f2(du.x), d1 = bf2_to_f2(du.y);
    float2 d2 = bf2_to_f2(du.z), d3 = bf2_to_f2(du.w);

    float m = -INFINITY, l = 0.0f;
    float a0 = 0.f, a1 = 0.f, a2 = 0.f, a3 = 0.f;
    float a4 = 0.f, a5 = 0.f, a6 = 0.f, a7 = 0.f;

    for (int base = beg; base < end; base += 64) {
        int nb = end - base;
        if (nb > 64) nb = 64;
        int gi = base + lane;
        bool valid = gi < end;
        int idx = valid ? (int)(pair_sorted[gi] & 0xffffu) : 0;
        float nv = norm[idx];

        // ---- pass A: parallel dots, 4 edges per iteration ----
        float ev = -INFINITY;
        for (int j = 0; j < nb; j += 4) {
            int jj = j + q;                          // quarter q -> edge j+q
            int sj = __shfl(idx, jj, 64);            // idx=0 for invalid lanes
            uint4 u = ((const uint4*)nfb)[(size_t)sj * 16 + ql];
            float2 f0 = bf2_to_f2(u.x), f1 = bf2_to_f2(u.y);
            float2 f2 = bf2_to_f2(u.z), f3 = bf2_to_f2(u.w);
            float part = f0.x * d0.x + f0.y * d0.y + f1.x * d1.x + f1.y * d1.y
                       + f2.x * d2.x + f2.y * d2.y + f3.x * d3.x + f3.y * d3.y;
            part += __shfl_xor(part, 1, 64);         // intra-quarter reduce
            part += __shfl_xor(part, 2, 64);
            part += __shfl_xor(part, 4, 64);
            part += __shfl_xor(part, 8, 64);
            // lane i grabs quarter (i&3)'s dot; keeps it when this iteration
            // computed edge i (i>>2 == j>>2)
            float v = __shfl(part, (lane & 3) << 4, 64);
            if ((lane >> 2) == (j >> 2)) ev = v;
        }
        ev = valid ? b * ev : -INFINITY;

        // ---- chunk softmax: one max-reduce + one online rescale ----
        float cm = ev;
        #pragma unroll
        for (int off = 1; off < 64; off <<= 1)
            cm = fmaxf(cm, __shfl_xor(cm, off, 64));
        float m2 = fmaxf(m, cm);
        float scale = expf(m - m2);   // first chunk: exp(-inf) = 0
        a0 *= scale; a1 *= scale; a2 *= scale; a3 *= scale;
        a4 *= scale; a5 *= scale; a6 *= scale; a7 *= scale;
        l *= scale;
        m = m2;

        float pe = expf(ev - m);      // 0 for invalid lanes
        l += pe;
        float pv = pe * nv;           // 0 for invalid lanes -> tail-safe

        // ---- pass B: weighted accumulation (rows L1-hot from pass A) ----
        #pragma unroll 4
        for (int j = 0; j < nb; j += 4) {
            int jj = j + q;
            float wj = __shfl(pv, jj, 64);           // 0 if jj >= nb
            int   sj = __shfl(idx, jj, 64);
            uint4 u = ((const uint4*)nfb)[(size_t)sj * 16 + ql];
            float2 f0 = bf2_to_f2(u.x), f1 = bf2_to_f2(u.y);
            float2 f2 = bf2_to_f2(u.z), f3 = bf2_to_f2(u.w);
            a0 += wj * f0.x;  a1 += wj * f0.y;
            a2 += wj * f1.x;  a3 += wj * f1.y;
            a4 += wj * f2.x;  a5 += wj * f2.y;
            a6 += wj * f3.x;  a7 += wj * f3.y;
        }
    }
    #pragma unroll
    for (int off = 1; off < 64; off <<= 1)
        l += __shfl_xor(l, off, 64);
    // merge the four quarter-wave accumulator sets (same dims in all quarters)
    a0 += __shfl_xor(a0, 16, 64); a0 += __shfl_xor(a0, 32, 64);
    a1 += __shfl_xor(a1, 16, 64); a1 += __shfl_xor(a1, 32, 64);
    a2 += __shfl_xor(a2, 16, 64); a2 += __shfl_xor(a2, 32, 64);
    a3 += __shfl_xor(a3, 16, 64); a3 += __shfl_xor(a3, 32, 64);
    a4 += __shfl_xor(a4, 16, 64); a4 += __shfl_xor(a4, 32, 64);
    a5 += __shfl_xor(a5, 16, 64); a5 += __shfl_xor(a5, 32, 64);
    a6 += __shfl_xor(a6, 16, 64); a6 += __shfl_xor(a6, 32, 64);
    a7 += __shfl_xor(a7, 16, 64); a7 += __shfl_xor(a7, 32, 64);
    float invl = (l > 0.0f) ? (1.0f / l) : 0.0f;
    if (q == 0) {
        float4* o = (float4*)out + (size_t)node * 32 + ql * 2;
        o[0] = make_float4(a0 * invl, a1 * invl, a2 * invl, a3 * invl);
        o[1] = make_float4(a4 * invl, a5 * invl, a6 * invl, a7 * invl);
    }
}

// ---------------------------------------------------------------------------
extern "C" void kernel_launch(void* const* d_in, const int* in_sizes, int n_in,
                              void* d_out, int out_size, void* d_ws, size_t ws_size,
                              hipStream_t stream) {
    const float* feat = (const float*)d_in[0];
    const int* src    = (const int*)d_in[1];
    const int* dst    = (const int*)d_in[2];
    const float* beta = (const float*)d_in[3];
    float* out = (float*)d_out;

    const int n_nodes = in_sizes[0] / D_FEAT;
    const int n_edges = in_sizes[1];
    const int epb = (n_edges + NB_HIST - 1) / NB_HIST;

    char* ws = (char*)d_ws;
    size_t off = 0;
    auto alloc = [&](size_t bytes) -> void* {
        void* p = ws + off;
        off += (bytes + 255) & ~(size_t)255;
        return p;
    };
    unsigned int*   nfb         = (unsigned int*)alloc((size_t)n_nodes * 64 * 4); // 2.56 MB
    float*          norm        = (float*)alloc((size_t)n_nodes * 4);
    int*            hist        = (int*)  alloc((size_t)NB_HIST * n_nodes * 4);   // 5.12 MB
    int*            cnt         = (int*)  alloc((size_t)n_nodes * 4);
    int*            offsets     = (int*)  alloc((size_t)(n_nodes + 1) * 4);
    unsigned short* lrank       = (unsigned short*)alloc((size_t)n_edges * 2);    // 1.28 MB
    unsigned int*   pair_sorted = (unsigned int*)alloc((size_t)n_edges * 4);      // 2.56 MB

    int nb_norm = (n_nodes * 64 + 255) / 256;
    norm_hist_kernel<<<NB_HIST + nb_norm, 256, 0, stream>>>(
        feat, dst, nfb, norm, hist, lrank, n_nodes, n_edges, epb);

    scanA_kernel<<<(n_nodes + 3) / 4, 256, 0, stream>>>(hist, cnt, n_nodes);

    scanB_kernel<<<1, 1024, 0, stream>>>(cnt, offsets, n_nodes);

    scatter_kernel<<<(n_edges + 255) / 256, 256, 0, stream>>>(
        src, dst, offsets, hist, lrank, pair_sorted, n_nodes, n_edges, epb);

    agg_kernel<<<(n_nodes + 3) / 4, 256, 0, stream>>>(
        nfb, norm, beta, offsets, pair_sorted, out, n_nodes);
}

// Round 12
// 132.599 us; speedup vs baseline: 4.3108x; 1.0569x over previous
//
#include <hip/hip_runtime.h>
#include <math.h>

#define D_FEAT 128
#define NB_HIST 128
#define N_NODES_MAX 10016   // LDS histogram capacity (problem has 10000)

// bf16 helpers -------------------------------------------------------------
__device__ __forceinline__ unsigned short f2bf(float x) {   // round-nearest-even
    unsigned int b = __float_as_uint(x);
    return (unsigned short)((b + 0x7fffu + ((b >> 16) & 1u)) >> 16);
}
__device__ __forceinline__ float2 bf2_to_f2(unsigned int u) {
    return make_float2(__uint_as_float(u << 16), __uint_as_float(u & 0xffff0000u));
}

// ---------------------------------------------------------------------------
// 1. Fused grid:
//    blocks [0, NB_HIST): per-block LDS histogram of dst — NO global atomics.
//      lrank[e] = rank of e within (block, dst); hist[b*n_nodes+n] = count.
//    blocks [NB_HIST, ...): convert rows to RAW bf16 + write invn = 1/||f||.
//    (Rows stay unnormalized; the dot is rescaled by invn_s*invn_d later —
//     same math, saves the per-element normalize multiply.)
// ---------------------------------------------------------------------------
__global__ __launch_bounds__(256) void norm_hist_kernel(
        const float* __restrict__ feat,
        const int* __restrict__ dst,
        unsigned int* __restrict__ nfb,
        float* __restrict__ invn,
        int* __restrict__ hist,
        unsigned short* __restrict__ lrank,
        int n_nodes, int n_edges, int epb) {
    __shared__ int lhist[N_NODES_MAX];
    if ((int)blockIdx.x < NB_HIST) {
        int b = blockIdx.x;
        for (int i = threadIdx.x; i < n_nodes; i += 256) lhist[i] = 0;
        __syncthreads();
        int e0 = b * epb;
        int e1 = e0 + epb;
        if (e1 > n_edges) e1 = n_edges;
        for (int e = e0 + (int)threadIdx.x; e < e1; e += 256) {
            int d = dst[e];
            lrank[e] = (unsigned short)atomicAdd(&lhist[d], 1);  // LDS atomic
        }
        __syncthreads();
        for (int i = threadIdx.x; i < n_nodes; i += 256)
            hist[b * n_nodes + i] = lhist[i];
    } else {
        int node = ((int)(blockIdx.x - NB_HIST) * 256 + (int)threadIdx.x) >> 6;
        int lane = threadIdx.x & 63;
        if (node >= n_nodes) return;
        float2 f = ((const float2*)feat)[node * 64 + lane];
        float ss = f.x * f.x + f.y * f.y;
        #pragma unroll
        for (int off = 1; off < 64; off <<= 1)
            ss += __shfl_xor(ss, off, 64);
        unsigned int lo = f2bf(f.x), hi = f2bf(f.y);
        nfb[node * 64 + lane] = (hi << 16) | lo;
        if (lane == 0) invn[node] = 1.0f / fmaxf(sqrtf(ss), 1e-12f);
    }
}

// ---------------------------------------------------------------------------
// 2a. scanA: one WAVE per node — lane b holds hist[b][node] and
//     hist[64+b][node]; two 64-lane scans with carry -> exclusive intra-node
//     base per hist block (in place), total -> cnt[node].
// ---------------------------------------------------------------------------
__global__ __launch_bounds__(256) void scanA_kernel(int* __restrict__ hist,
                                                    int* __restrict__ cnt,
                                                    int n_nodes) {
    int node = (int)(blockIdx.x * blockDim.x + threadIdx.x) >> 6;
    int lane = threadIdx.x & 63;
    if (node >= n_nodes) return;
    int idx0 = lane * n_nodes + node;
    int idx1 = (64 + lane) * n_nodes + node;
    int v0 = hist[idx0];
    int v1 = hist[idx1];
    int incl0 = v0;
    #pragma unroll
    for (int off = 1; off < 64; off <<= 1) {
        int t = __shfl_up(incl0, off, 64);
        if (lane >= off) incl0 += t;
    }
    int tot0 = __shfl(incl0, 63, 64);
    int incl1 = v1;
    #pragma unroll
    for (int off = 1; off < 64; off <<= 1) {
        int t = __shfl_up(incl1, off, 64);
        if (lane >= off) incl1 += t;
    }
    hist[idx0] = incl0 - v0;                 // exclusive prefix, b = lane
    hist[idx1] = tot0 + incl1 - v1;          // exclusive prefix, b = 64+lane
    if (lane == 63) cnt[node] = tot0 + incl1;  // node degree
}

// ---------------------------------------------------------------------------
// 2b. scanB: exclusive scan of cnt -> offsets. One 1024-thread block.
// ---------------------------------------------------------------------------
__global__ __launch_bounds__(1024) void scanB_kernel(const int* __restrict__ cnt,
                                                     int* __restrict__ offsets, int n) {
    __shared__ int wsum[16];
    __shared__ int total;
    int t = threadIdx.x;
    const int per = (n + 1023) >> 10;
    int beg = t * per;
    int end = beg + per;
    if (beg > n) beg = n;
    if (end > n) end = n;
    int local[16];
    int s = 0;
    for (int i = beg; i < end; ++i) { int v = cnt[i]; local[i - beg] = v; s += v; }
    int lane = t & 63, wid = t >> 6;
    int incl = s;
    #pragma unroll
    for (int off = 1; off < 64; off <<= 1) {
        int v = __shfl_up(incl, off, 64);
        if (lane >= off) incl += v;
    }
    if (lane == 63) wsum[wid] = incl;
    __syncthreads();
    if (t == 0) {
        int run = 0;
        #pragma unroll
        for (int w = 0; w < 16; ++w) { int v = wsum[w]; wsum[w] = run; run += v; }
        total = run;
    }
    __syncthreads();
    int base = wsum[wid] + (incl - s);
    for (int i = beg; i < end; ++i) { offsets[i] = base; base += local[i - beg]; }
    if (t == 0) offsets[n] = total;
}

// ---------------------------------------------------------------------------
// 3. Scatter (no atomics): pos = offsets[d] + hist[b][d] + lrank[e].
//    One 2B store: src id only (dst of a sorted position == its node).
// ---------------------------------------------------------------------------
__global__ void scatter_kernel(const int* __restrict__ src,
                               const int* __restrict__ dst,
                               const int* __restrict__ offsets,
                               const int* __restrict__ hist,
                               const unsigned short* __restrict__ lrank,
                               unsigned short* __restrict__ src_sorted,
                               int n_nodes, int n_edges, int epb) {
    int e = blockIdx.x * blockDim.x + threadIdx.x;
    if (e >= n_edges) return;
    int d = dst[e];
    int b = e / epb;
    int pos = offsets[d] + hist[b * n_nodes + d] + (int)lrank[e];
    src_sorted[pos] = (unsigned short)src[e];
}

// ---------------------------------------------------------------------------
// 4. SINGLE-PASS fused dot + exp + aggregation. One wave per node.
//    KEY: e = beta*cos is bounded (|cos|<=1), so exp(e) never overflows —
//    the segment-max subtraction is mathematically removable (p = e^e / sum
//    is identical to the max-shifted form). This collapses the two-phase
//    online-softmax structure into ONE gather per edge:
//      quarter q handles edge j+q: load src row (uint4/lane, 16 lanes =
//      full row), dot vs register-held dst row, 4-step intra-quarter reduce
//      (all 16 lanes get the dot), w = __expf(dot*invn_s*(beta*invn_d)),
//      accumulate w*row from the SAME registers. No second gather, no
//      deposit shuffle, no max/rescale machinery.
// ---------------------------------------------------------------------------
__global__ void agg_kernel(const unsigned int* __restrict__ nfb,
                           const float* __restrict__ invn,
                           const float* __restrict__ beta,
                           const int* __restrict__ offsets,
                           const unsigned short* __restrict__ src_sorted,
                           float* __restrict__ out, int n_nodes) {
    int node = (int)(blockIdx.x * blockDim.x + threadIdx.x) >> 6;
    int lane = threadIdx.x & 63;
    if (node >= n_nodes) return;
    int beg = offsets[node];
    int end = offsets[node + 1];
    int q  = lane >> 4;          // quarter id 0..3 -> edge j+q
    int ql = lane & 15;          // dims 8*ql .. 8*ql+7
    float bd = beta[0] * invn[node];   // fold beta and 1/||f_d||

    // dst row: each quarter holds the full 128-dim row (16 lanes x uint4)
    uint4 du = ((const uint4*)nfb)[(size_t)node * 16 + ql];
    float2 d0 = bf2_to_f2(du.x), d1 = bf2_to_f2(du.y);
    float2 d2 = bf2_to_f2(du.z), d3 = bf2_to_f2(du.w);

    float l = 0.0f;
    float a0 = 0.f, a1 = 0.f, a2 = 0.f, a3 = 0.f;
    float a4 = 0.f, a5 = 0.f, a6 = 0.f, a7 = 0.f;

    for (int base = beg; base < end; base += 64) {
        int nb = end - base;
        if (nb > 64) nb = 64;
        int gi = base + lane;
        bool valid = gi < end;
        int idx = valid ? (int)src_sorted[gi] : 0;
        float ivm = valid ? invn[idx] : 0.0f;   // 0 marks invalid edges

        #pragma unroll 4
        for (int j = 0; j < nb; j += 4) {
            int jj = j + q;                         // quarter q -> edge j+q
            int   sj  = __shfl(idx, jj, 64);        // 0 for invalid -> row 0
            float inj = __shfl(ivm, jj, 64);        // 0 for invalid
            uint4 u = ((const uint4*)nfb)[(size_t)sj * 16 + ql];
            float2 f0 = bf2_to_f2(u.x), f1 = bf2_to_f2(u.y);
            float2 f2 = bf2_to_f2(u.z), f3 = bf2_to_f2(u.w);
            float part = f0.x * d0.x + f0.y * d0.y + f1.x * d1.x + f1.y * d1.y
                       + f2.x * d2.x + f2.y * d2.y + f3.x * d3.x + f3.y * d3.y;
            part += __shfl_xor(part, 1, 64);        // intra-quarter reduce
            part += __shfl_xor(part, 2, 64);
            part += __shfl_xor(part, 4, 64);
            part += __shfl_xor(part, 8, 64);        // all 16 lanes hold dot
            float w = __expf(part * inj * bd);
            w = (inj > 0.0f) ? w : 0.0f;            // mask invalid edges
            l += w;
            a0 += w * f0.x;  a1 += w * f0.y;
            a2 += w * f1.x;  a3 += w * f1.y;
            a4 += w * f2.x;  a5 += w * f2.y;
            a6 += w * f3.x;  a7 += w * f3.y;
        }
    }
    // each edge's w was accumulated by all 16 lanes of its quarter ->
    // full 64-lane reduce gives 16 * sum(w)
    #pragma unroll
    for (int off = 1; off < 64; off <<= 1)
        l += __shfl_xor(l, off, 64);
    // merge the four quarter-wave accumulator sets (same dims in all quarters)
    a0 += __shfl_xor(a0, 16, 64); a0 += __shfl_xor(a0, 32, 64);
    a1 += __shfl_xor(a1, 16, 64); a1 += __shfl_xor(a1, 32, 64);
    a2 += __shfl_xor(a2, 16, 64); a2 += __shfl_xor(a2, 32, 64);
    a3 += __shfl_xor(a3, 16, 64); a3 += __shfl_xor(a3, 32, 64);
    a4 += __shfl_xor(a4, 16, 64); a4 += __shfl_xor(a4, 32, 64);
    a5 += __shfl_xor(a5, 16, 64); a5 += __shfl_xor(a5, 32, 64);
    a6 += __shfl_xor(a6, 16, 64); a6 += __shfl_xor(a6, 32, 64);
    a7 += __shfl_xor(a7, 16, 64); a7 += __shfl_xor(a7, 32, 64);
    float invl = (l > 0.0f) ? (16.0f / l) : 0.0f;
    if (q == 0) {
        float4* o = (float4*)out + (size_t)node * 32 + ql * 2;
        o[0] = make_float4(a0 * invl, a1 * invl, a2 * invl, a3 * invl);
        o[1] = make_float4(a4 * invl, a5 * invl, a6 * invl, a7 * invl);
    }
}

// ---------------------------------------------------------------------------
extern "C" void kernel_launch(void* const* d_in, const int* in_sizes, int n_in,
                              void* d_out, int out_size, void* d_ws, size_t ws_size,
                              hipStream_t stream) {
    const float* feat = (const float*)d_in[0];
    const int* src    = (const int*)d_in[1];
    const int* dst    = (const int*)d_in[2];
    const float* beta = (const float*)d_in[3];
    float* out = (float*)d_out;

    const int n_nodes = in_sizes[0] / D_FEAT;
    const int n_edges = in_sizes[1];
    const int epb = (n_edges + NB_HIST - 1) / NB_HIST;

    char* ws = (char*)d_ws;
    size_t off = 0;
    auto alloc = [&](size_t bytes) -> void* {
        void* p = ws + off;
        off += (bytes + 255) & ~(size_t)255;
        return p;
    };
    unsigned int*   nfb        = (unsigned int*)alloc((size_t)n_nodes * 64 * 4); // 2.56 MB
    float*          invn       = (float*)alloc((size_t)n_nodes * 4);
    int*            hist       = (int*)  alloc((size_t)NB_HIST * n_nodes * 4);   // 5.12 MB
    int*            cnt        = (int*)  alloc((size_t)n_nodes * 4);
    int*            offsets    = (int*)  alloc((size_t)(n_nodes + 1) * 4);
    unsigned short* lrank      = (unsigned short*)alloc((size_t)n_edges * 2);    // 1.28 MB
    unsigned short* src_sorted = (unsigned short*)alloc((size_t)n_edges * 2);    // 1.28 MB

    int nb_norm = (n_nodes * 64 + 255) / 256;
    norm_hist_kernel<<<NB_HIST + nb_norm, 256, 0, stream>>>(
        feat, dst, nfb, invn, hist, lrank, n_nodes, n_edges, epb);

    scanA_kernel<<<(n_nodes + 3) / 4, 256, 0, stream>>>(hist, cnt, n_nodes);

    scanB_kernel<<<1, 1024, 0, stream>>>(cnt, offsets, n_nodes);

    scatter_kernel<<<(n_edges + 255) / 256, 256, 0, stream>>>(
        src, dst, offsets, hist, lrank, src_sorted, n_nodes, n_edges, epb);

    agg_kernel<<<(n_nodes + 3) / 4, 256, 0, stream>>>(
        nfb, invn, beta, offsets, src_sorted, out, n_nodes);
}